// Round 1
// baseline (625.386 us; speedup 1.0000x reference)
//
#include <hip/hip_runtime.h>
#include <cstdint>
#include <cstddef>

#define KTOP 1000
#define CAP  2048   // gather buffer: top-1000 + exact-tie slack

// ---------------- Kernel 1: softmax scores + SSD box decode ----------------
__global__ void decode_kernel(const float* __restrict__ loc,
                              const float* __restrict__ conf,
                              const float* __restrict__ prior,
                              float* __restrict__ scores,   // [B][C-1][P]
                              float* __restrict__ cs,       // [B][P][4] center-size
                              int B, int C, int P) {
#pragma clang fp contract(off)
    int t = blockIdx.x * blockDim.x + threadIdx.x;
    if (t >= B * P) return;
    int b = t / P;
    int p = t - b * P;

    // softmax over class dim (C small, <=8)
    float x[8];
    float m = -INFINITY;
    for (int c = 0; c < C; ++c) {
        x[c] = conf[((size_t)b * C + c) * P + p];
        m = fmaxf(m, x[c]);
    }
    float sum = 0.f;
    for (int c = 0; c < C; ++c) {          // sequential sum, matches linear reduce
        x[c] = expf(x[c] - m);
        sum += x[c];
    }
    for (int c = 1; c < C; ++c) {
        scores[((size_t)b * (C - 1) + (c - 1)) * P + p] = x[c] / sum;
    }

    // decode: cxcy = prior_cxcy + (loc*0.1)*prior_wh ; wh = prior_wh * exp(loc*0.2)
    float l0 = loc[((size_t)b * 4 + 0) * P + p];
    float l1 = loc[((size_t)b * 4 + 1) * P + p];
    float l2 = loc[((size_t)b * 4 + 2) * P + p];
    float l3 = loc[((size_t)b * 4 + 3) * P + p];
    float pcx = prior[(size_t)p * 4 + 0];
    float pcy = prior[(size_t)p * 4 + 1];
    float pw  = prior[(size_t)p * 4 + 2];
    float ph  = prior[(size_t)p * 4 + 3];

    float cx = pcx + (l0 * 0.1f) * pw;
    float cy = pcy + (l1 * 0.1f) * ph;
    float w  = pw * expf(l2 * 0.2f);
    float h  = ph * expf(l3 * 0.2f);

    size_t o = ((size_t)b * P + p) * 4;
    cs[o + 0] = cx;
    cs[o + 1] = cy;
    cs[o + 2] = w;
    cs[o + 3] = h;
}

// ------------- Kernel 2: per-(b,c) top-k select + sort + NMS + pack -------------
__global__ void __launch_bounds__(1024)
nms_kernel(const float* __restrict__ scores,   // [B*Cfg][P]
           const float* __restrict__ cs,       // [B][P][4]
           const float* __restrict__ cthp,
           const float* __restrict__ nthp,
           float* __restrict__ out,            // [B*Cfg][KTOP][5]
           int P, int Cfg) {
#pragma clang fp contract(off)
    const int bc  = blockIdx.x;
    const int b   = bc / Cfg;
    const int tid = threadIdx.x;
    const int NT  = blockDim.x;
    const float cth = *cthp;
    const float nth = *nthp;
    const float* s = scores + (size_t)bc * P;

    __shared__ unsigned long long sbuf[CAP];          // 16 KB sort keys
    __shared__ float bx1[KTOP], by1[KTOP], bx2[KTOP], by2[KTOP], bar[KTOP]; // 20 KB
    __shared__ float ssc[KTOP];                       // 4 KB
    __shared__ int   sid[KTOP];                       // 4 KB
    __shared__ int   keep[KTOP];                      // 4 KB
    __shared__ int   spos[KTOP];                      // 4 KB
    __shared__ unsigned hist[256];                    // 1 KB
    __shared__ unsigned s_prefix;
    __shared__ int s_remaining, s_takeall, s_cnt;

    // zero the output tile up front (harness poisons d_out with 0xAA)
    for (int r = tid; r < KTOP; r += NT) {
        size_t ob = ((size_t)bc * KTOP + r) * 5;
        for (int j = 0; j < 5; ++j) out[ob + j] = 0.f;
    }

    if (tid == 0) { s_prefix = 0u; s_remaining = KTOP; s_takeall = 0; s_cnt = 0; }
    __syncthreads();

    // ---- radix select: find the KTOP-th largest score bit pattern ----
    for (int pass = 0; pass < 4; ++pass) {
        for (int i = tid; i < 256; i += NT) hist[i] = 0u;
        __syncthreads();
        if (!s_takeall) {
            unsigned pref = s_prefix;
            int shift = 24 - 8 * pass;
            for (int p = tid; p < P; p += NT) {
                float v = s[p];
                if (!(v >= cth)) continue;              // mask below conf_thresh
                unsigned key = __float_as_uint(v);      // positive floats: bit order = value order
                if (pass > 0 && (key >> (32 - 8 * pass)) != pref) continue;
                atomicAdd(&hist[(key >> shift) & 255u], 1u);
            }
        }
        __syncthreads();
        if (tid == 0 && !s_takeall) {
            int rem = s_remaining;
            unsigned cum = 0;
            int bin;
            for (bin = 255; bin >= 0; --bin) {
                unsigned c = hist[bin];
                if (cum + c >= (unsigned)rem) {
                    s_prefix = (s_prefix << 8) | (unsigned)bin;
                    s_remaining = rem - (int)cum;
                    break;
                }
                cum += c;
            }
            if (bin < 0) s_takeall = 1;   // fewer than KTOP valid candidates
        }
        __syncthreads();
    }

    // ---- gather all candidates with key >= pivot (or all valid) ----
    {
        unsigned pivot = s_prefix;
        int takeall = s_takeall;
        for (int p = tid; p < P; p += NT) {
            float v = s[p];
            if (!(v >= cth)) continue;
            unsigned key = __float_as_uint(v);
            if (!takeall && key < pivot) continue;
            int pos = atomicAdd(&s_cnt, 1);
            if (pos < CAP)
                sbuf[pos] = ((unsigned long long)key << 32) | (unsigned)(~(unsigned)p);
        }
    }
    __syncthreads();
    int M = s_cnt < CAP ? s_cnt : CAP;
    int nsel = M < KTOP ? M : KTOP;

    // ---- bitonic sort ascending; top ranks read from the back ----
    int n = 1024;
    while (n < M) n <<= 1;
    for (int i = tid; i < n; i += NT)
        if (i >= M) sbuf[i] = 0ull;
    __syncthreads();
    for (unsigned k = 2; k <= (unsigned)n; k <<= 1) {
        for (unsigned j = k >> 1; j > 0; j >>= 1) {
            for (unsigned i = tid; i < (unsigned)n; i += NT) {
                unsigned ixj = i ^ j;
                if (ixj > i) {
                    bool up = ((i & k) == 0u);
                    unsigned long long a = sbuf[i], bb = sbuf[ixj];
                    if ((a > bb) == up) { sbuf[i] = bb; sbuf[ixj] = a; }
                }
            }
            __syncthreads();
        }
    }

    // ---- load selected boxes, compute point form + area ----
    for (int r = tid; r < nsel; r += NT) {
        unsigned long long e = sbuf[n - 1 - r];
        unsigned key = (unsigned)(e >> 32);
        int idx = (int)(~(unsigned)e);
        ssc[r] = __uint_as_float(key);
        sid[r] = idx;
        keep[r] = 1;
        size_t cb = ((size_t)b * P + idx) * 4;
        float cx = cs[cb + 0], cy = cs[cb + 1], w = cs[cb + 2], h = cs[cb + 3];
        float x1 = cx - w / 2.f, y1 = cy - h / 2.f;
        float x2 = cx + w / 2.f, y2 = cy + h / 2.f;
        bx1[r] = x1; by1[r] = y1; bx2[r] = x2; by2[r] = y2;
        float ww = fmaxf(x2 - x1, 0.f), hh = fmaxf(y2 - y1, 0.f);
        bar[r] = ww * hh;
    }

    // ---- greedy NMS, sequential over ranks ----
    for (int i = 0; i < nsel; ++i) {
        __syncthreads();                       // make iteration i-1's clears visible
        if (keep[i] == 0) continue;            // uniform branch
        float xi1 = bx1[i], yi1 = by1[i], xi2 = bx2[i], yi2 = by2[i], ai = bar[i];
        for (int j = i + 1 + tid; j < nsel; j += NT) {
            if (!keep[j]) continue;
            float w = fmaxf(fminf(xi2, bx2[j]) - fmaxf(xi1, bx1[j]), 0.f);
            float h = fmaxf(fminf(yi2, by2[j]) - fmaxf(yi1, by1[j]), 0.f);
            float inter = w * h;
            float uni = ai + bar[j] - inter;
            float iou = inter / fmaxf(uni, 1e-12f);
            if (iou > nth) keep[j] = 0;
        }
    }
    __syncthreads();

    // ---- compact positions ----
    if (tid == 0) {
        int c = 0;
        for (int i = 0; i < nsel; ++i) { spos[i] = c; c += keep[i]; }
    }
    __syncthreads();

    // ---- write packed rows (score, cx, cy, w, h) ----
    for (int i = tid; i < nsel; i += NT) {
        if (!keep[i]) continue;
        int r = spos[i];
        size_t ob = ((size_t)bc * KTOP + r) * 5;
        size_t cb = ((size_t)b * P + sid[i]) * 4;
        out[ob + 0] = ssc[i];
        out[ob + 1] = cs[cb + 0];
        out[ob + 2] = cs[cb + 1];
        out[ob + 3] = cs[cb + 2];
        out[ob + 4] = cs[cb + 3];
    }
}

// ------------------------------- launcher -------------------------------
extern "C" void kernel_launch(void* const* d_in, const int* in_sizes, int n_in,
                              void* d_out, int out_size, void* d_ws, size_t ws_size,
                              hipStream_t stream) {
    (void)n_in; (void)out_size; (void)ws_size;
    const float* loc   = (const float*)d_in[0];
    const float* conf  = (const float*)d_in[1];
    const float* prior = (const float*)d_in[2];
    const float* cth   = (const float*)d_in[3];
    const float* nth   = (const float*)d_in[4];
    float* out = (float*)d_out;

    int P = in_sizes[2] / 4;                 // priors
    int B = in_sizes[0] / (4 * P);           // images
    int C = in_sizes[1] / (B * P);           // classes incl. background
    int Cfg = C - 1;

    float* scores = (float*)d_ws;                          // B*Cfg*P floats
    float* cs     = scores + (size_t)B * Cfg * P;          // B*P*4 floats

    int n1 = B * P;
    decode_kernel<<<(n1 + 255) / 256, 256, 0, stream>>>(loc, conf, prior, scores, cs, B, C, P);
    nms_kernel<<<B * Cfg, 1024, 0, stream>>>(scores, cs, cth, nth, out, P, Cfg);
}